// Round 1
// baseline (77.513 us; speedup 1.0000x reference)
//
#include <hip/hip_runtime.h>
#include <math.h>

#define B_DIM   64
#define T_DIM   1024
#define E_DIM   512
#define DL_DIM  1024
#define DA_DIM  128
#define CL_DIM  32
#define KW      31

// ws layout (float offsets)
#define WS_WCOMB 0            // 128*31 = 3968
#define WS_BCOMB 3968         // 128
#define WS_PL    4096         // 64*128 = 8192
#define WS_EN    12288        // 64*1024 = 65536
// total: 77824 floats = 311296 bytes

// ---------------------------------------------------------------------------
// K1: processed_lstm[b][a] = dot(lstm[b], W_lstm[a]);
//     Wcomb[a][k] = sum_c W_loc[a][c]*conv_w[c][k];
//     bcomb[a]    = b_loc[a] + sum_c W_loc[a][c]*conv_b[c]
// ---------------------------------------------------------------------------
__global__ __launch_bounds__(128) void prep_kernel(
    const float* __restrict__ lstm,    // [B,1,DL]
    const float* __restrict__ W_lstm,  // [DA,DL]
    const float* __restrict__ conv_w,  // [CL,1,KW]
    const float* __restrict__ conv_b,  // [CL]
    const float* __restrict__ W_loc,   // [DA,CL]
    const float* __restrict__ b_loc,   // [DA]
    float* __restrict__ ws) {
  const int blk = blockIdx.x;
  const int tid = threadIdx.x; // 0..127
  if (blk < B_DIM) {
    const float4* lv = (const float4*)(lstm + (size_t)blk * DL_DIM);
    const float4* wv = (const float4*)(W_lstm + (size_t)tid * DL_DIM);
    float acc = 0.f;
#pragma unroll 4
    for (int i = 0; i < DL_DIM / 4; ++i) {
      float4 a = lv[i], b = wv[i];
      acc = fmaf(a.x, b.x, acc);
      acc = fmaf(a.y, b.y, acc);
      acc = fmaf(a.z, b.z, acc);
      acc = fmaf(a.w, b.w, acc);
    }
    ws[WS_PL + blk * DA_DIM + tid] = acc;
  } else {
    const int a = tid;
    float wl[CL_DIM];
#pragma unroll
    for (int c = 0; c < CL_DIM; ++c) wl[c] = W_loc[a * CL_DIM + c];
    float bc = b_loc[a];
#pragma unroll
    for (int c = 0; c < CL_DIM; ++c) bc = fmaf(wl[c], conv_b[c], bc);
    ws[WS_BCOMB + a] = bc;
    for (int k = 0; k < KW; ++k) {
      float s = 0.f;
#pragma unroll
      for (int c = 0; c < CL_DIM; ++c) s = fmaf(wl[c], conv_w[c * KW + k], s);
      ws[WS_WCOMB + a * KW + k] = s;
    }
  }
}

// ---------------------------------------------------------------------------
// K2: energies[b][t] = b_e + sum_a W_e[a] * tanh( pl[b][a] + bcomb[a]
//        + sum_k Wcomb[a][k]*awc_pad[b][t+k-15] + peo[b][t][a] )
// grid (8,64): 8 chunks of 128 t's. block 256 = 4 waves; each wave 32 t's.
// lane owns a0=lane, a1=lane+64 (Wcomb rows register-cached).
// ---------------------------------------------------------------------------
#define TCHUNK 128
__global__ __launch_bounds__(256) void energy_kernel(
    const float* __restrict__ peo,  // [B,T,DA]
    const float* __restrict__ awc,  // [B,T]
    const float* __restrict__ W_e,  // [DA]
    const float* __restrict__ b_e,  // [1]
    float* __restrict__ ws) {
  const int b = blockIdx.y;
  const int t0 = blockIdx.x * TCHUNK;
  const int tid = threadIdx.x;
  const int lane = tid & 63;
  const int wave = tid >> 6;

  __shared__ float s_awc[TCHUNK + KW - 1]; // 158

  for (int i = tid; i < TCHUNK + KW - 1; i += 256) {
    int g = t0 - (KW / 2) + i;
    s_awc[i] = (g >= 0 && g < T_DIM) ? awc[b * T_DIM + g] : 0.f;
  }
  __syncthreads();

  const int a0 = lane, a1 = lane + 64;
  float wc0[KW], wc1[KW];
#pragma unroll
  for (int k = 0; k < KW; ++k) {
    wc0[k] = ws[WS_WCOMB + a0 * KW + k];
    wc1[k] = ws[WS_WCOMB + a1 * KW + k];
  }
  const float base0 = ws[WS_PL + b * DA_DIM + a0] + ws[WS_BCOMB + a0];
  const float base1 = ws[WS_PL + b * DA_DIM + a1] + ws[WS_BCOMB + a1];
  const float we0 = W_e[a0], we1 = W_e[a1];
  const float be = b_e[0];

#pragma unroll 2
  for (int i = 0; i < TCHUNK / 4; ++i) {
    const int tl = wave * (TCHUNK / 4) + i; // local t
    const int t = t0 + tl;
    const float* p = peo + ((size_t)b * T_DIM + t) * DA_DIM;
    const float p0 = p[a0];
    const float p1 = p[a1];
    float s0 = base0, s1 = base1;
#pragma unroll
    for (int k = 0; k < KW; ++k) {
      const float aw = s_awc[tl + k];
      s0 = fmaf(aw, wc0[k], s0);
      s1 = fmaf(aw, wc1[k], s1);
    }
    const float x0 = s0 + p0;
    const float x1 = s1 + p1;
    // overflow-safe tanh: sign(x)*(1-e)/(1+e), e = exp(-2|x|)
    const float e0 = __expf(-2.f * fabsf(x0));
    const float e1 = __expf(-2.f * fabsf(x1));
    const float th0 = __builtin_copysignf((1.f - e0) / (1.f + e0), x0);
    const float th1 = __builtin_copysignf((1.f - e1) / (1.f + e1), x1);
    float v = fmaf(th0, we0, th1 * we1);
#pragma unroll
    for (int off = 32; off > 0; off >>= 1) v += __shfl_xor(v, off);
    if (lane == 0) ws[WS_EN + b * T_DIM + t] = v + be;
  }
}

// ---------------------------------------------------------------------------
// K3: softmax over T (in-block, energies are L2-resident) + weighted sum of
// encoder_output. grid (8,64): 8 e-chunks of 64 floats. block 256.
// ---------------------------------------------------------------------------
__global__ __launch_bounds__(256) void context_kernel(
    const float* __restrict__ enc,  // [B,T,E]
    const float* __restrict__ ws,
    float* __restrict__ out) {      // [B*E context][B*T weights]
  const int b = blockIdx.y;
  const int ec = blockIdx.x;  // 0..7
  const int tid = threadIdx.x;

  __shared__ float s_red[256];
  __shared__ float s_w[T_DIM];
  __shared__ float4 s_acc[16][16];

  // ---- softmax over the 1024 energies of row b ----
  const float* en = ws + WS_EN + (size_t)b * T_DIM;
  const float4 ev = ((const float4*)en)[tid];
  float m = fmaxf(fmaxf(ev.x, ev.y), fmaxf(ev.z, ev.w));
  s_red[tid] = m;
  __syncthreads();
  for (int s = 128; s > 0; s >>= 1) {
    if (tid < s) s_red[tid] = fmaxf(s_red[tid], s_red[tid + s]);
    __syncthreads();
  }
  const float M = s_red[0];
  __syncthreads();
  float4 ex;
  ex.x = __expf(ev.x - M);
  ex.y = __expf(ev.y - M);
  ex.z = __expf(ev.z - M);
  ex.w = __expf(ev.w - M);
  s_red[tid] = ex.x + ex.y + ex.z + ex.w;
  __syncthreads();
  for (int s = 128; s > 0; s >>= 1) {
    if (tid < s) s_red[tid] += s_red[tid + s];
    __syncthreads();
  }
  const float inv = 1.f / s_red[0];
  float4 wv;
  wv.x = ex.x * inv; wv.y = ex.y * inv; wv.z = ex.z * inv; wv.w = ex.w * inv;
  ((float4*)s_w)[tid] = wv;
  if (ec == 0) ((float4*)(out + B_DIM * E_DIM + (size_t)b * T_DIM))[tid] = wv;
  __syncthreads();

  // ---- context: acc[e] = sum_t w[t] * enc[b][t][e] ----
  const int c = tid & 15;   // float4 col within chunk (16 f4 = 64 floats)
  const int r = tid >> 4;   // 0..15
  const float4* ep = (const float4*)(enc + (size_t)b * T_DIM * E_DIM) + ec * 16 + c;
  float4 acc = make_float4(0.f, 0.f, 0.f, 0.f);
#pragma unroll 8
  for (int t = r; t < T_DIM; t += 16) {
    const float4 v = ep[(size_t)t * (E_DIM / 4)];
    const float w = s_w[t];
    acc.x = fmaf(w, v.x, acc.x);
    acc.y = fmaf(w, v.y, acc.y);
    acc.z = fmaf(w, v.z, acc.z);
    acc.w = fmaf(w, v.w, acc.w);
  }
  s_acc[r][c] = acc;
  __syncthreads();
  if (r == 0) {
    float4 s = s_acc[0][c];
#pragma unroll
    for (int i = 1; i < 16; ++i) {
      const float4 q = s_acc[i][c];
      s.x += q.x; s.y += q.y; s.z += q.z; s.w += q.w;
    }
    ((float4*)(out + (size_t)b * E_DIM))[ec * 16 + c] = s;
  }
}

// ---------------------------------------------------------------------------
extern "C" void kernel_launch(void* const* d_in, const int* in_sizes, int n_in,
                              void* d_out, int out_size, void* d_ws, size_t ws_size,
                              hipStream_t stream) {
  const float* enc    = (const float*)d_in[0];   // [64,1024,512]
  const float* peo    = (const float*)d_in[1];   // [64,1024,128]
  const float* lstm   = (const float*)d_in[2];   // [64,1,1024]
  const float* awc    = (const float*)d_in[3];   // [64,1024]
  const float* W_lstm = (const float*)d_in[4];   // [128,1024]
  const float* conv_w = (const float*)d_in[5];   // [32,1,31]
  const float* conv_b = (const float*)d_in[6];   // [32]
  const float* W_loc  = (const float*)d_in[7];   // [128,32]
  const float* b_loc  = (const float*)d_in[8];   // [128]
  const float* W_e    = (const float*)d_in[9];   // [1,128]
  const float* b_e    = (const float*)d_in[10];  // [1]
  float* out = (float*)d_out;
  float* ws  = (float*)d_ws;

  prep_kernel<<<B_DIM + 1, 128, 0, stream>>>(lstm, W_lstm, conv_w, conv_b,
                                             W_loc, b_loc, ws);
  energy_kernel<<<dim3(T_DIM / TCHUNK, B_DIM), 256, 0, stream>>>(peo, awc, W_e,
                                                                 b_e, ws);
  context_kernel<<<dim3(8, B_DIM), 256, 0, stream>>>(enc, ws, out);
}

// Round 2
// 69.457 us; speedup vs baseline: 1.1160x; 1.1160x over previous
//
#include <hip/hip_runtime.h>
#include <math.h>

#define B_DIM   64
#define T_DIM   1024
#define E_DIM   512
#define DL_DIM  1024
#define DA_DIM  128
#define CL_DIM  32
#define KW      31

// ws layout (float offsets)
#define WS_WCOMB 0            // 128*31 = 3968
#define WS_BCOMB 3968         // 128
#define WS_PL    4096         // 64*128 = 8192
#define WS_EN    12288        // 64*1024 = 65536
#define WS_W     77824        // 64*1024 = 65536  (softmax weights)
// total: 143360 floats = 573 KB

// ---------------------------------------------------------------------------
// K1: blocks 0..63: processed_lstm[b][a] = dot(lstm[b], W_lstm[a])
//     block 64:     Wcomb[a][k] = sum_c W_loc[a][c]*conv_w[c][k];
//                   bcomb[a]    = b_loc[a] + sum_c W_loc[a][c]*conv_b[c]
// 256 threads: 2 threads per 'a', each a 512-length half-dot, shfl combine.
// ---------------------------------------------------------------------------
__global__ __launch_bounds__(256) void prep_kernel(
    const float* __restrict__ lstm,    // [B,1,DL]
    const float* __restrict__ W_lstm,  // [DA,DL]
    const float* __restrict__ conv_w,  // [CL,1,KW]
    const float* __restrict__ conv_b,  // [CL]
    const float* __restrict__ W_loc,   // [DA,CL]
    const float* __restrict__ b_loc,   // [DA]
    float* __restrict__ ws) {
  const int blk = blockIdx.x;
  const int tid = threadIdx.x;
  if (blk < B_DIM) {
    const int a = tid >> 1;
    const int h = tid & 1;
    const float4* lv = (const float4*)(lstm + (size_t)blk * DL_DIM + h * (DL_DIM / 2));
    const float4* wv = (const float4*)(W_lstm + (size_t)a * DL_DIM + h * (DL_DIM / 2));
    float acc = 0.f;
#pragma unroll 8
    for (int i = 0; i < DL_DIM / 8; ++i) {
      float4 x = lv[i], y = wv[i];
      acc = fmaf(x.x, y.x, acc);
      acc = fmaf(x.y, y.y, acc);
      acc = fmaf(x.z, y.z, acc);
      acc = fmaf(x.w, y.w, acc);
    }
    acc += __shfl_xor(acc, 1);
    if (h == 0) ws[WS_PL + blk * DA_DIM + a] = acc;
  } else if (tid < DA_DIM) {
    const int a = tid;
    float wl[CL_DIM];
#pragma unroll
    for (int c = 0; c < CL_DIM; ++c) wl[c] = W_loc[a * CL_DIM + c];
    float bc = b_loc[a];
#pragma unroll
    for (int c = 0; c < CL_DIM; ++c) bc = fmaf(wl[c], conv_b[c], bc);
    ws[WS_BCOMB + a] = bc;
    for (int k = 0; k < KW; ++k) {
      float s = 0.f;
#pragma unroll
      for (int c = 0; c < CL_DIM; ++c) s = fmaf(wl[c], conv_w[c * KW + k], s);
      ws[WS_WCOMB + a * KW + k] = s;
    }
  }
}

// ---------------------------------------------------------------------------
// K2: energies[b][t] = b_e + sum_a W_e[a] * tanh( pl[b][a] + bcomb[a]
//        + sum_k Wcomb[a][k]*awc_pad[b][t+k-15] + peo[b][t][a] )
// grid (16,64): chunks of 64 t. block 256 = 4 waves; each wave 16 t's.
// lane owns a0=2*lane, a1=2*lane+1 (float2 peo loads, Wcomb rows in regs).
// ---------------------------------------------------------------------------
#define TCHUNK 64
__global__ __launch_bounds__(256) void energy_kernel(
    const float* __restrict__ peo,  // [B,T,DA]
    const float* __restrict__ awc,  // [B,T]
    const float* __restrict__ W_e,  // [DA]
    const float* __restrict__ b_e,  // [1]
    float* __restrict__ ws) {
  const int b = blockIdx.y;
  const int t0 = blockIdx.x * TCHUNK;
  const int tid = threadIdx.x;
  const int lane = tid & 63;
  const int wave = tid >> 6;

  __shared__ float s_awc[TCHUNK + KW - 1]; // 94

  for (int i = tid; i < TCHUNK + KW - 1; i += 256) {
    int g = t0 - (KW / 2) + i;
    s_awc[i] = (g >= 0 && g < T_DIM) ? awc[b * T_DIM + g] : 0.f;
  }
  __syncthreads();

  const int a0 = 2 * lane, a1 = 2 * lane + 1;
  float wc0[KW], wc1[KW];
#pragma unroll
  for (int k = 0; k < KW; ++k) {
    wc0[k] = ws[WS_WCOMB + a0 * KW + k];
    wc1[k] = ws[WS_WCOMB + a1 * KW + k];
  }
  const float base0 = ws[WS_PL + b * DA_DIM + a0] + ws[WS_BCOMB + a0];
  const float base1 = ws[WS_PL + b * DA_DIM + a1] + ws[WS_BCOMB + a1];
  const float we0 = W_e[a0], we1 = W_e[a1];
  const float be = b_e[0];

  float keep = 0.f;
#pragma unroll 2
  for (int i = 0; i < TCHUNK / 4; ++i) {
    const int tl = wave * (TCHUNK / 4) + i; // local t
    const int t = t0 + tl;
    const float2 p = *(const float2*)(peo + ((size_t)b * T_DIM + t) * DA_DIM + a0);
    float s0 = base0, s1 = base1;
#pragma unroll
    for (int k = 0; k < KW; ++k) {
      const float aw = s_awc[tl + k];
      s0 = fmaf(aw, wc0[k], s0);
      s1 = fmaf(aw, wc1[k], s1);
    }
    const float x0 = s0 + p.x;
    const float x1 = s1 + p.y;
    // overflow-safe tanh: sign(x)*(1-e)*rcp(1+e), e = exp(-2|x|)
    const float e0 = __expf(-2.f * fabsf(x0));
    const float e1 = __expf(-2.f * fabsf(x1));
    const float th0 = __builtin_copysignf((1.f - e0) * __builtin_amdgcn_rcpf(1.f + e0), x0);
    const float th1 = __builtin_copysignf((1.f - e1) * __builtin_amdgcn_rcpf(1.f + e1), x1);
    float v = fmaf(th0, we0, th1 * we1);
#pragma unroll
    for (int off = 32; off > 0; off >>= 1) v += __shfl_xor(v, off);
    if (lane == i) keep = v; // iteration i's sum parked in lane i
  }
  if (lane < TCHUNK / 4)
    ws[WS_EN + b * T_DIM + t0 + wave * (TCHUNK / 4) + lane] = keep + be;
}

// ---------------------------------------------------------------------------
// K2.5: softmax over T per b. grid 64, block 256 (float4 per thread).
// Writes weights to ws (for K3) and to out.
// ---------------------------------------------------------------------------
__global__ __launch_bounds__(256) void softmax_kernel(
    const float* __restrict__ ws_in, float* __restrict__ ws,
    float* __restrict__ out) {
  const int b = blockIdx.x;
  const int tid = threadIdx.x;
  const int lane = tid & 63;
  const int wave = tid >> 6;
  __shared__ float s4[4];

  const float4 ev = ((const float4*)(ws_in + WS_EN + (size_t)b * T_DIM))[tid];
  float m = fmaxf(fmaxf(ev.x, ev.y), fmaxf(ev.z, ev.w));
#pragma unroll
  for (int off = 32; off > 0; off >>= 1) m = fmaxf(m, __shfl_xor(m, off));
  if (lane == 0) s4[wave] = m;
  __syncthreads();
  const float M = fmaxf(fmaxf(s4[0], s4[1]), fmaxf(s4[2], s4[3]));
  __syncthreads();
  float4 ex;
  ex.x = __expf(ev.x - M);
  ex.y = __expf(ev.y - M);
  ex.z = __expf(ev.z - M);
  ex.w = __expf(ev.w - M);
  float s = ex.x + ex.y + ex.z + ex.w;
#pragma unroll
  for (int off = 32; off > 0; off >>= 1) s += __shfl_xor(s, off);
  if (lane == 0) s4[wave] = s;
  __syncthreads();
  const float inv = 1.f / (s4[0] + s4[1] + s4[2] + s4[3]);
  float4 wv;
  wv.x = ex.x * inv; wv.y = ex.y * inv; wv.z = ex.z * inv; wv.w = ex.w * inv;
  ((float4*)(ws + WS_W + (size_t)b * T_DIM))[tid] = wv;
  ((float4*)(out + B_DIM * E_DIM + (size_t)b * T_DIM))[tid] = wv;
}

// ---------------------------------------------------------------------------
// K3: context[b][e] = sum_t w[t] * enc[b][t][e]. Pure streaming.
// grid (16,64): 16 column-chunks of 32 floats (8 float4). block 256.
// ---------------------------------------------------------------------------
__global__ __launch_bounds__(256) void context_kernel(
    const float* __restrict__ enc,  // [B,T,E]
    const float* __restrict__ ws,
    float* __restrict__ out) {
  const int b = blockIdx.y;
  const int ec = blockIdx.x;  // 0..15
  const int tid = threadIdx.x;

  __shared__ float s_w[T_DIM];
  __shared__ float4 s_acc[32][8];

  ((float4*)s_w)[tid] = ((const float4*)(ws + WS_W + (size_t)b * T_DIM))[tid];
  __syncthreads();

  const int c = tid & 7;    // float4 col within chunk
  const int r = tid >> 3;   // 0..31
  const float4* ep = (const float4*)(enc + (size_t)b * T_DIM * E_DIM) + ec * 8 + c;
  float4 acc = make_float4(0.f, 0.f, 0.f, 0.f);
#pragma unroll 8
  for (int t = r; t < T_DIM; t += 32) {
    const float4 v = ep[(size_t)t * (E_DIM / 4)];
    const float w = s_w[t];
    acc.x = fmaf(w, v.x, acc.x);
    acc.y = fmaf(w, v.y, acc.y);
    acc.z = fmaf(w, v.z, acc.z);
    acc.w = fmaf(w, v.w, acc.w);
  }
  s_acc[r][c] = acc;
  __syncthreads();
  if (tid < 64) {
    const int cc = tid & 7;
    const int i = tid >> 3;  // 0..7
    float4 sv = s_acc[i][cc];
#pragma unroll
    for (int j = 8; j < 32; j += 8) {
      const float4 q = s_acc[i + j][cc];
      sv.x += q.x; sv.y += q.y; sv.z += q.z; sv.w += q.w;
    }
    s_acc[i][cc] = sv;
  }
  __syncthreads();
  if (tid < 8) {
    float4 sv = s_acc[0][tid];
#pragma unroll
    for (int i = 1; i < 8; ++i) {
      const float4 q = s_acc[i][tid];
      sv.x += q.x; sv.y += q.y; sv.z += q.z; sv.w += q.w;
    }
    ((float4*)(out + (size_t)b * E_DIM))[ec * 8 + tid] = sv;
  }
}

// ---------------------------------------------------------------------------
extern "C" void kernel_launch(void* const* d_in, const int* in_sizes, int n_in,
                              void* d_out, int out_size, void* d_ws, size_t ws_size,
                              hipStream_t stream) {
  const float* enc    = (const float*)d_in[0];   // [64,1024,512]
  const float* peo    = (const float*)d_in[1];   // [64,1024,128]
  const float* lstm   = (const float*)d_in[2];   // [64,1,1024]
  const float* awc    = (const float*)d_in[3];   // [64,1024]
  const float* W_lstm = (const float*)d_in[4];   // [128,1024]
  const float* conv_w = (const float*)d_in[5];   // [32,1,31]
  const float* conv_b = (const float*)d_in[6];   // [32]
  const float* W_loc  = (const float*)d_in[7];   // [128,32]
  const float* b_loc  = (const float*)d_in[8];   // [128]
  const float* W_e    = (const float*)d_in[9];   // [1,128]
  const float* b_e    = (const float*)d_in[10];  // [1]
  float* out = (float*)d_out;
  float* ws  = (float*)d_ws;

  prep_kernel<<<B_DIM + 1, 256, 0, stream>>>(lstm, W_lstm, conv_w, conv_b,
                                             W_loc, b_loc, ws);
  energy_kernel<<<dim3(T_DIM / TCHUNK, B_DIM), 256, 0, stream>>>(peo, awc, W_e,
                                                                 b_e, ws);
  softmax_kernel<<<B_DIM, 256, 0, stream>>>(ws, ws, out);
  context_kernel<<<dim3(16, B_DIM), 256, 0, stream>>>(enc, ws, out);
}